// Round 8
// baseline (430.934 us; speedup 1.0000x reference)
//
#include <hip/hip_runtime.h>
#include <stdint.h>

static constexpr int kNU = 100000;
static constexpr int kNI = 50000;
static constexpr int kE  = 500000;
static constexpr int kC  = 128;
static constexpr int kB  = 1024;
static constexpr int kNBK = 256;  // binning blocks per direction
static constexpr int kCap = 4096; // max edges per coarse bucket (mean 2560)

typedef __attribute__((ext_vector_type(8))) short bf16x8;
typedef __attribute__((ext_vector_type(4))) float f32x4;

__device__ __forceinline__ unsigned short f2bf(float f) {
  unsigned u = __float_as_uint(f);
  unsigned r = (u + 0x7fffu + ((u >> 16) & 1u)) >> 16;
  return (unsigned short)r;
}

// Empty-asm register pin: makes the value an opaque def so the compiler cannot
// sink/rematerialize the producing load (rounds 6-7: it de-pipelined every
// source-level prefetch, VGPR_Count 88/68 proved W+A never stayed resident).
template <typename T>
__device__ __forceinline__ void pin(T& x) { asm volatile("" : "+v"(x)); }

// ---- fp32 -> bf16 feature conversion (both tables in one launch) ----
__global__ void cvt_kernel(const float* __restrict__ xu, const float* __restrict__ xi,
                           unsigned short* __restrict__ fu, unsigned short* __restrict__ fi) {
  int i = blockIdx.x * blockDim.x + threadIdx.x;  // float4 index
  const int nu4 = kNU * kC / 4;
  const int ni4 = kNI * kC / 4;
  if (i < nu4) {
    float4 v = ((const float4*)xu)[i];
    ushort4 o; o.x = f2bf(v.x); o.y = f2bf(v.y); o.z = f2bf(v.z); o.w = f2bf(v.w);
    ((ushort4*)fu)[i] = o;
  } else if (i < nu4 + ni4) {
    int j = i - nu4;
    float4 v = ((const float4*)xi)[j];
    ushort4 o; o.x = f2bf(v.x); o.y = f2bf(v.y); o.z = f2bf(v.z); o.w = f2bf(v.w);
    ((ushort4*)fi)[j] = o;
  }
}

// ---- weight prep: wcat[m][n][k] bf16, m = l*2+t; k<128 -> w_rel^T, k>=128 -> w_root^T ----
__global__ void prep_w_kernel(const float* __restrict__ wrel, const float* __restrict__ wroot,
                              unsigned short* __restrict__ wcat) {
  int id = blockIdx.x * 256 + threadIdx.x;  // 4*128*256 = 131072
  int m = id >> 15;
  int n = (id >> 8) & 127;
  int k = id & 255;
  float v = (k < 128) ? wrel[(m * 128 + k) * 128 + n] : wroot[(m * 128 + (k - 128)) * 128 + n];
  wcat[id] = f2bf(v);
}

// ================= LDS-binned CSR build (no global atomics), both dirs =================
__global__ void binA_kernel(const int* __restrict__ dst_i, const int* __restrict__ dst_u,
                            int* __restrict__ bh_i, int* __restrict__ bh_u) {
  __shared__ int h[256];
  int b = blockIdx.x;
  const int* dst;
  int shift;
  int* bh;
  int blk;
  if (b < kNBK) { dst = dst_i; shift = 8; bh = bh_i; blk = b; }
  else          { dst = dst_u; shift = 9; bh = bh_u; blk = b - kNBK; }
  int tid = threadIdx.x;
  h[tid] = 0;
  __syncthreads();
  int chunk = (kE + kNBK - 1) / kNBK;
  int beg = blk * chunk;
  int end = min(kE, beg + chunk);
  for (int i = beg + tid; i < end; i += 256) atomicAdd(&h[dst[i] >> shift], 1);
  __syncthreads();
  bh[blk * 256 + tid] = h[tid];
}

__global__ void binB_kernel(const int* __restrict__ bh_i, int* __restrict__ bo_i,
                            int* __restrict__ base_i, const int* __restrict__ bh_u,
                            int* __restrict__ bo_u, int* __restrict__ base_u) {
  __shared__ int s[256];
  const int* bh;
  int* bo;
  int* base;
  if (blockIdx.x == 0) { bh = bh_i; bo = bo_i; base = base_i; }
  else                 { bh = bh_u; bo = bo_u; base = base_u; }
  int t = threadIdx.x;
  int run = 0;
  for (int b = 0; b < kNBK; ++b) {
    int v = bh[b * 256 + t];
    bo[b * 256 + t] = run;
    run += v;
  }
  s[t] = run;
  __syncthreads();
  for (int m = 1; m < 256; m <<= 1) {
    int tv = 0;
    if (t >= m) tv = s[t - m];
    __syncthreads();
    s[t] += tv;
    __syncthreads();
  }
  base[t] = s[t] - run;
  if (t == 255) base[256] = s[255];
}

__global__ void binC_kernel(const int* __restrict__ src_i, const int* __restrict__ dst_i,
                            const int* __restrict__ bo_i, const int* __restrict__ base_i,
                            unsigned* __restrict__ packed_i, const int* __restrict__ src_u,
                            const int* __restrict__ dst_u, const int* __restrict__ bo_u,
                            const int* __restrict__ base_u, unsigned* __restrict__ packed_u) {
  __shared__ int cur[256];
  int b = blockIdx.x;
  const int *src, *dst, *bo, *base;
  unsigned* packed;
  int shift, blk;
  if (b < kNBK) { src = src_i; dst = dst_i; bo = bo_i; base = base_i; packed = packed_i; shift = 8; blk = b; }
  else          { src = src_u; dst = dst_u; bo = bo_u; base = base_u; packed = packed_u; shift = 9; blk = b - kNBK; }
  int tid = threadIdx.x;
  cur[tid] = base[tid] + bo[blk * 256 + tid];
  __syncthreads();
  int chunk = (kE + kNBK - 1) / kNBK;
  int beg = blk * chunk;
  int end = min(kE, beg + chunk);
  int mask = (1 << shift) - 1;
  for (int i = beg + tid; i < end; i += 256) {
    int d = dst[i];
    int p = atomicAdd(&cur[d >> shift], 1);
    packed[p] = (unsigned)src[i] | ((unsigned)(d & mask) << 17);
  }
}

__launch_bounds__(256)
__global__ void binD_kernel(const unsigned* __restrict__ packed_i, const int* __restrict__ base_i,
                            int* __restrict__ col_i, int* __restrict__ rowptr_i,
                            const unsigned* __restrict__ packed_u, const int* __restrict__ base_u,
                            int* __restrict__ col_u, int* __restrict__ rowptr_u) {
  __shared__ unsigned ent[kCap];
  __shared__ int srt[kCap];
  __shared__ int hist[512];
  __shared__ int cur[512];
  int b = blockIdx.x;
  const unsigned* packed;
  const int* base;
  int* col;
  int* rowptr;
  int bsize, Nd, bb;
  if (b < 196) { packed = packed_i; base = base_i; col = col_i; rowptr = rowptr_i; bsize = 256; Nd = kNI; bb = b; }
  else         { packed = packed_u; base = base_u; col = col_u; rowptr = rowptr_u; bsize = 512; Nd = kNU; bb = b - 196; }
  int tid = threadIdx.x;
  int seg_beg = base[bb], seg_end = base[bb + 1];
  int cnt = seg_end - seg_beg;
  if (cnt > kCap) cnt = kCap;
  hist[tid] = 0;
  hist[tid + 256] = 0;
  __syncthreads();
  for (int i = tid; i < cnt; i += 256) {
    unsigned e = packed[seg_beg + i];
    ent[i] = e;
    atomicAdd(&hist[e >> 17], 1);
  }
  __syncthreads();
  for (int d = 1; d < 512; d <<= 1) {
    int idx = (tid + 1) * 2 * d - 1;
    if (idx < 512) hist[idx] += hist[idx - d];
    __syncthreads();
  }
  if (tid == 0) hist[511] = 0;
  __syncthreads();
  for (int d = 256; d >= 1; d >>= 1) {
    int idx = (tid + 1) * 2 * d - 1;
    if (idx < 512) {
      int tmp = hist[idx - d];
      hist[idx - d] = hist[idx];
      hist[idx] += tmp;
    }
    __syncthreads();
  }
  for (int j = tid; j < bsize; j += 256) {
    int n = bb * bsize + j;
    if (n < Nd) rowptr[n] = seg_beg + hist[j];
  }
  if (bb == 195 && tid == 0) rowptr[Nd] = seg_end;
  cur[tid] = hist[tid];
  cur[tid + 256] = hist[tid + 256];
  __syncthreads();
  for (int i = tid; i < cnt; i += 256) {
    unsigned e = ent[i];
    int p = atomicAdd(&cur[e >> 17], 1);
    srt[p] = (int)(e & 0x1FFFFu);
  }
  __syncthreads();
  for (int i = tid; i < cnt; i += 256) col[seg_beg + i] = srt[i];
}

// ---- pull aggregation v3: quarter-wave per row, 16B/lane gathers, index prefetch ----
__global__ void pull3_kernel(const int* __restrict__ rp_i, const int* __restrict__ col_i,
                             const unsigned short* __restrict__ ft_i, unsigned short* __restrict__ ag_i,
                             const int* __restrict__ rp_u, const int* __restrict__ col_u,
                             const unsigned short* __restrict__ ft_u, unsigned short* __restrict__ ag_u,
                             int nbi) {
  int b = blockIdx.x;
  const int *rowptr, *col;
  const unsigned short* feat;
  unsigned short* agg;
  int Nd, rbase;
  if (b < nbi) { rowptr = rp_i; col = col_i; feat = ft_i; agg = ag_i; Nd = kNI; rbase = b * 16; }
  else         { rowptr = rp_u; col = col_u; feat = ft_u; agg = ag_u; Nd = kNU; rbase = (b - nbi) * 16; }
  int tid = threadIdx.x;
  int wv = tid >> 6;
  int lane = tid & 63;
  int qrow = lane >> 4;
  int qoff = lane & 15;
  int r = rbase + wv * 4 + qrow;
  int beg = 0, end = 0;
  if (r < Nd) {
    beg = rowptr[r];
    end = rowptr[r + 1];
  }
  float acc[8];
#pragma unroll
  for (int c = 0; c < 8; ++c) acc[c] = 0.f;

  int i0 = 0, i1 = 0, i2 = 0, i3 = 0;
  if (beg < end) {  // col padded with 4 zero ints past kE -> over-reads safe
    i0 = col[beg];
    i1 = col[beg + 1];
    i2 = col[beg + 2];
    i3 = col[beg + 3];
  }
  int choff = qoff * 8;
  for (int j = beg; j < end; j += 4) {
    int rem = end - j;
    int n0 = i0, n1 = i1, n2 = i2, n3 = i3;
    if (j + 4 < end) {
      n0 = col[j + 4];
      n1 = col[j + 5];
      n2 = col[j + 6];
      n3 = col[j + 7];
    }
    uint4 g0 = *(const uint4*)(feat + (size_t)i0 * kC + choff);
    uint4 g1 = *(const uint4*)(feat + (size_t)i1 * kC + choff);
    uint4 g2 = *(const uint4*)(feat + (size_t)i2 * kC + choff);
    uint4 g3 = *(const uint4*)(feat + (size_t)i3 * kC + choff);
    if (rem < 2) { g1.x = 0; g1.y = 0; g1.z = 0; g1.w = 0; }
    if (rem < 3) { g2.x = 0; g2.y = 0; g2.z = 0; g2.w = 0; }
    if (rem < 4) { g3.x = 0; g3.y = 0; g3.z = 0; g3.w = 0; }
#define ACC8(g)                                          \
    acc[0] += __uint_as_float((g).x << 16);              \
    acc[1] += __uint_as_float((g).x & 0xffff0000u);      \
    acc[2] += __uint_as_float((g).y << 16);              \
    acc[3] += __uint_as_float((g).y & 0xffff0000u);      \
    acc[4] += __uint_as_float((g).z << 16);              \
    acc[5] += __uint_as_float((g).z & 0xffff0000u);      \
    acc[6] += __uint_as_float((g).w << 16);              \
    acc[7] += __uint_as_float((g).w & 0xffff0000u);
    ACC8(g0)
    ACC8(g1)
    ACC8(g2)
    ACC8(g3)
#undef ACC8
    i0 = n0; i1 = n1; i2 = n2; i3 = n3;
  }
  if (r < Nd) {
    uint4 o;
    o.x = (unsigned)f2bf(acc[0]) | ((unsigned)f2bf(acc[1]) << 16);
    o.y = (unsigned)f2bf(acc[2]) | ((unsigned)f2bf(acc[3]) << 16);
    o.z = (unsigned)f2bf(acc[4]) | ((unsigned)f2bf(acc[5]) << 16);
    o.w = (unsigned)f2bf(acc[6]) | ((unsigned)f2bf(acc[7]) << 16);
    *(uint4*)(agg + (size_t)r * kC + choff) = o;
  }
}

// ---- MFMA GEMM v5: gemm4 + register pins so the compiler cannot de-pipeline ----
// wave wv owns cols [wv*32, wv*32+32): W slice (16 bf16x8 = 64 VGPR) pinned resident.
// Per tile: 8 pinned A-frag prefetch loads in flight across the epilogue + barrier
// (barrier waits lgkmcnt only). Grid 512 = exactly 2 blocks/CU, persistent.
__launch_bounds__(256, 2)
__global__ void gemm5_kernel(
    const unsigned short* __restrict__ ag_i, const unsigned short* __restrict__ ft_i,
    const unsigned short* __restrict__ wc_i, const float* __restrict__ bs_i,
    const float* __restrict__ gm_i, const float* __restrict__ bt_i,
    unsigned short* __restrict__ out_i,
    const unsigned short* __restrict__ ag_u, const unsigned short* __restrict__ ft_u,
    const unsigned short* __restrict__ wc_u, const float* __restrict__ bs_u,
    const float* __restrict__ gm_u, const float* __restrict__ bt_u,
    unsigned short* __restrict__ out_u) {
  __shared__ float red[2][2][64];  // [parity][s1|s2][wave*16+row]
  constexpr int Gi = 256, Gu = 256;
  constexpr int Ti = kNI / 16;  // 3125
  constexpr int Tu = kNU / 16;  // 6250
  int b = blockIdx.x;
  const unsigned short *agg, *feat, *wcat;
  const float *bias, *gamma, *beta;
  unsigned short* out;
  int T, G, t0;
  if (b < Gi) {
    agg = ag_i; feat = ft_i; wcat = wc_i; bias = bs_i; gamma = gm_i; beta = bt_i; out = out_i;
    T = Ti; G = Gi; t0 = b;
  } else {
    agg = ag_u; feat = ft_u; wcat = wc_u; bias = bs_u; gamma = gm_u; beta = bt_u; out = out_u;
    T = Tu; G = Gu; t0 = b - Gi;
  }
  int tid = threadIdx.x;
  int lane = tid & 63;
  int wv = tid >> 6;
  int q = lane >> 4;
  int c0 = lane & 15;

  // W slice in registers, pinned (loaded once, L2-hot)
  bf16x8 w0[8], w1[8];
  {
    const unsigned short* wr0 = wcat + (wv * 32 + c0) * 256 + q * 8;
    const unsigned short* wr1 = wr0 + 16 * 256;
#pragma unroll
    for (int ks = 0; ks < 8; ++ks) {
      w0[ks] = *(const bf16x8*)(wr0 + ks * 32);
      w1[ks] = *(const bf16x8*)(wr1 + ks * 32);
      pin(w0[ks]);
      pin(w1[ks]);
    }
  }
  float bc0 = bias[wv * 32 + c0], bc1 = bias[wv * 32 + 16 + c0];
  float gc0 = gamma[wv * 32 + c0], gc1 = gamma[wv * 32 + 16 + c0];
  float ec0 = beta[wv * 32 + c0], ec1 = beta[wv * 32 + 16 + c0];

  f32x4 acc0 = (f32x4){0.f, 0.f, 0.f, 0.f};
  f32x4 acc1 = (f32x4){0.f, 0.f, 0.f, 0.f};
  bf16x8 a[8], an[8];

  {  // preload first tile, pinned
    size_t rb = (size_t)(t0 * 16 + c0) * kC + q * 8;
#pragma unroll
    for (int ks = 0; ks < 8; ++ks) {
      const unsigned short* s = (ks < 4) ? agg : feat;
      a[ks] = *(const bf16x8*)(s + rb + (ks & 3) * 32);
      pin(a[ks]);
    }
  }
  int par = 0;
  for (int t = t0; t < T; t += G) {
    int tn = (t + G < T) ? (t + G) : t;  // clamp: last iter re-reads (harmless)
    size_t rbn = (size_t)(tn * 16 + c0) * kC + q * 8;
#pragma unroll
    for (int ks = 0; ks < 8; ++ks) {
      const unsigned short* s = (ks < 4) ? agg : feat;
      an[ks] = *(const bf16x8*)(s + rbn + (ks & 3) * 32);
      pin(an[ks]);  // force issue here; vmcnt wait lands at the a=an rotation
    }
#pragma unroll
    for (int ks = 0; ks < 8; ++ks) {
      acc0 = __builtin_amdgcn_mfma_f32_16x16x32_bf16(a[ks], w0[ks], acc0, 0, 0, 0);
      acc1 = __builtin_amdgcn_mfma_f32_16x16x32_bf16(a[ks], w1[ks], acc1, 0, 0, 0);
    }
    // ---- LN epilogue (C/D: col=c0, row=q*4+reg; rows of this tile = t*16+row) ----
    float x0[4], x1[4];
#pragma unroll
    for (int reg = 0; reg < 4; ++reg) {
      float v0 = acc0[reg] + bc0;
      float v1 = acc1[reg] + bc1;
      x0[reg] = v0;
      x1[reg] = v1;
      float s1 = v0 + v1;
      float s2 = v0 * v0 + v1 * v1;
#pragma unroll
      for (int m = 1; m < 16; m <<= 1) {
        s1 += __shfl_xor(s1, m, 64);
        s2 += __shfl_xor(s2, m, 64);
      }
      if (c0 == 0) {
        red[par][0][wv * 16 + q * 4 + reg] = s1;
        red[par][1][wv * 16 + q * 4 + reg] = s2;
      }
    }
    __builtin_amdgcn_s_waitcnt(0xC07F);  // lgkmcnt(0) only — keep vmcnt prefetch alive
    __builtin_amdgcn_s_barrier();
#pragma unroll
    for (int reg = 0; reg < 4; ++reg) {
      int row = q * 4 + reg;
      float S1 = red[par][0][row] + red[par][0][16 + row] + red[par][0][32 + row] +
                 red[par][0][48 + row];
      float S2 = red[par][1][row] + red[par][1][16 + row] + red[par][1][32 + row] +
                 red[par][1][48 + row];
      float mu = S1 * (1.f / 128.f);
      float rs = rsqrtf(S2 * (1.f / 128.f) - mu * mu + 1e-5f);
      float o0 = fmaxf((x0[reg] - mu) * rs * gc0 + ec0, 0.f);
      float o1 = fmaxf((x1[reg] - mu) * rs * gc1 + ec1, 0.f);
      unsigned short h0 = f2bf(o0), h1 = f2bf(o1);
      unsigned up0 = __shfl_xor((unsigned)h0, 1, 64);
      unsigned up1 = __shfl_xor((unsigned)h1, 1, 64);
      if ((lane & 1) == 0) {
        size_t rowg = (size_t)(t * 16 + row) * kC;
        *(unsigned*)(out + rowg + wv * 32 + c0) = (unsigned)h0 | (up0 << 16);
        *(unsigned*)(out + rowg + wv * 32 + 16 + c0) = (unsigned)h1 | (up1 << 16);
      }
    }
#pragma unroll
    for (int ks = 0; ks < 8; ++ks) {
      a[ks] = an[ks];
      pin(a[ks]);
    }
    acc0 = (f32x4){0.f, 0.f, 0.f, 0.f};
    acc1 = (f32x4){0.f, 0.f, 0.f, 0.f};
    par ^= 1;
  }
}

// ---- final head: out[r] = feat_u[r,:] . lin_w + lin_b ----
__global__ void head_kernel(const unsigned short* __restrict__ fu, const float* __restrict__ lw,
                            const float* __restrict__ lb, float* __restrict__ out) {
  int w = (blockIdx.x * blockDim.x + threadIdx.x) >> 6;
  int lane = threadIdx.x & 63;
  if (w >= kB) return;
  unsigned v = *(const unsigned*)(fu + w * kC + lane * 2);
  float2 ww = *(const float2*)(lw + lane * 2);
  float p = __uint_as_float(v << 16) * ww.x + __uint_as_float(v & 0xffff0000u) * ww.y;
#pragma unroll
  for (int m = 1; m < 64; m <<= 1) p += __shfl_xor(p, m, 64);
  if (lane == 0) out[w] = p + lb[0];
}

extern "C" void kernel_launch(void* const* d_in, const int* in_sizes, int n_in,
                              void* d_out, int out_size, void* d_ws, size_t ws_size,
                              hipStream_t stream) {
  const float* x_user = (const float*)d_in[0];
  const float* x_item = (const float*)d_in[1];
  const int* e_ui_src = (const int*)d_in[2];
  const int* e_ui_dst = (const int*)d_in[3];
  const int* e_iu_src = (const int*)d_in[4];
  const int* e_iu_dst = (const int*)d_in[5];
  const float* w_rel  = (const float*)d_in[6];
  const float* w_root = (const float*)d_in[7];
  const float* bvec   = (const float*)d_in[8];
  const float* ln_g   = (const float*)d_in[9];
  const float* ln_b   = (const float*)d_in[10];
  const float* lin_w  = (const float*)d_in[11];
  const float* lin_b  = (const float*)d_in[12];

  char* p = (char*)d_ws;
  auto carve = [&](size_t bytes) -> char* {
    char* r = p;
    p += (bytes + 255) & ~size_t(255);
    return r;
  };
  unsigned short* fu[2] = {(unsigned short*)carve((size_t)kNU * kC * 2),
                           (unsigned short*)carve((size_t)kNU * kC * 2)};
  unsigned short* fi[2] = {(unsigned short*)carve((size_t)kNI * kC * 2),
                           (unsigned short*)carve((size_t)kNI * kC * 2)};
  unsigned short* agg_i = (unsigned short*)carve((size_t)kNI * kC * 2);
  unsigned short* agg_u = (unsigned short*)carve((size_t)kNU * kC * 2);
  unsigned short* wcat  = (unsigned short*)carve((size_t)4 * 128 * 256 * 2);
  int* bh_i   = (int*)carve((size_t)kNBK * 256 * 4);
  int* bo_i   = (int*)carve((size_t)kNBK * 256 * 4);
  int* bh_u   = (int*)carve((size_t)kNBK * 256 * 4);
  int* bo_u   = (int*)carve((size_t)kNBK * 256 * 4);
  int* base_i = (int*)carve(257 * 4);
  int* base_u = (int*)carve(257 * 4);
  unsigned* packed_i = (unsigned*)carve((size_t)kE * 4);
  unsigned* packed_u = (unsigned*)carve((size_t)kE * 4);
  int* col_i    = (int*)carve((size_t)(kE + 4) * 4);
  int* col_u    = (int*)carve((size_t)(kE + 4) * 4);
  int* rowptr_i = (int*)carve((size_t)(kNI + 1) * 4);
  int* rowptr_u = (int*)carve((size_t)(kNU + 1) * 4);

  int cvtN = (kNU * kC + kNI * kC) / 4;
  cvt_kernel<<<(cvtN + 255) / 256, 256, 0, stream>>>(x_user, x_item, fu[0], fi[0]);
  prep_w_kernel<<<512, 256, 0, stream>>>(w_rel, w_root, wcat);

  binA_kernel<<<2 * kNBK, 256, 0, stream>>>(e_ui_dst, e_iu_dst, bh_i, bh_u);
  binB_kernel<<<2, 256, 0, stream>>>(bh_i, bo_i, base_i, bh_u, bo_u, base_u);
  binC_kernel<<<2 * kNBK, 256, 0, stream>>>(e_ui_src, e_ui_dst, bo_i, base_i, packed_i,
                                            e_iu_src, e_iu_dst, bo_u, base_u, packed_u);
  binD_kernel<<<392, 256, 0, stream>>>(packed_i, base_i, col_i, rowptr_i,
                                       packed_u, base_u, col_u, rowptr_u);
  hipMemsetAsync(col_i + kE, 0, 16, stream);
  hipMemsetAsync(col_u + kE, 0, 16, stream);

  int nbi_p = (kNI + 15) / 16;  // 3125
  int nbu_p = (kNU + 15) / 16;  // 6250

  int cur = 0;
  for (int l = 0; l < 2; ++l) {
    pull3_kernel<<<nbi_p + nbu_p, 256, 0, stream>>>(rowptr_i, col_i, fu[cur], agg_i,
                                                    rowptr_u, col_u, fi[cur], agg_u, nbi_p);
    gemm5_kernel<<<512, 256, 0, stream>>>(
        agg_i, fi[cur], wcat + (size_t)(l * 2 + 0) * 128 * 256,
        bvec + (size_t)(l * 2 + 0) * kC, ln_g + (size_t)(l * 2 + 1) * kC,
        ln_b + (size_t)(l * 2 + 1) * kC, fi[1 - cur],
        agg_u, fu[cur], wcat + (size_t)(l * 2 + 1) * 128 * 256,
        bvec + (size_t)(l * 2 + 1) * kC, ln_g + (size_t)(l * 2 + 0) * kC,
        ln_b + (size_t)(l * 2 + 0) * kC, fu[1 - cur]);
    cur ^= 1;
  }

  head_kernel<<<(kB + 3) / 4, 256, 0, stream>>>(fu[cur], lin_w, lin_b, (float*)d_out);
}

// Round 9
// 320.018 us; speedup vs baseline: 1.3466x; 1.3466x over previous
//
#include <hip/hip_runtime.h>
#include <stdint.h>

static constexpr int kNU = 100000;
static constexpr int kNI = 50000;
static constexpr int kE  = 500000;
static constexpr int kC  = 128;
static constexpr int kB  = 1024;
static constexpr int kNBK = 256;  // binning blocks per direction
static constexpr int kCap = 4096; // max edges per coarse bucket (mean 2560)
static constexpr int kWS = 264;   // LDS W row stride in shorts (16B aligned, breaks 16-way conflicts)

typedef __attribute__((ext_vector_type(8))) short bf16x8;
typedef __attribute__((ext_vector_type(4))) float f32x4;

__device__ __forceinline__ unsigned short f2bf(float f) {
  unsigned u = __float_as_uint(f);
  unsigned r = (u + 0x7fffu + ((u >> 16) & 1u)) >> 16;
  return (unsigned short)r;
}

// ---- fp32 -> bf16 feature conversion (both tables in one launch) ----
__global__ void cvt_kernel(const float* __restrict__ xu, const float* __restrict__ xi,
                           unsigned short* __restrict__ fu, unsigned short* __restrict__ fi) {
  int i = blockIdx.x * blockDim.x + threadIdx.x;  // float4 index
  const int nu4 = kNU * kC / 4;
  const int ni4 = kNI * kC / 4;
  if (i < nu4) {
    float4 v = ((const float4*)xu)[i];
    ushort4 o; o.x = f2bf(v.x); o.y = f2bf(v.y); o.z = f2bf(v.z); o.w = f2bf(v.w);
    ((ushort4*)fu)[i] = o;
  } else if (i < nu4 + ni4) {
    int j = i - nu4;
    float4 v = ((const float4*)xi)[j];
    ushort4 o; o.x = f2bf(v.x); o.y = f2bf(v.y); o.z = f2bf(v.z); o.w = f2bf(v.w);
    ((ushort4*)fi)[j] = o;
  }
}

// ---- weight prep: wcat[m][n][k] bf16, m = l*2+t; k<128 -> w_rel^T, k>=128 -> w_root^T ----
__global__ void prep_w_kernel(const float* __restrict__ wrel, const float* __restrict__ wroot,
                              unsigned short* __restrict__ wcat) {
  int id = blockIdx.x * 256 + threadIdx.x;  // 4*128*256 = 131072
  int m = id >> 15;
  int n = (id >> 8) & 127;
  int k = id & 255;
  float v = (k < 128) ? wrel[(m * 128 + k) * 128 + n] : wroot[(m * 128 + (k - 128)) * 128 + n];
  wcat[id] = f2bf(v);
}

// ================= LDS-binned CSR build (no global atomics), both dirs =================
__global__ void binA_kernel(const int* __restrict__ dst_i, const int* __restrict__ dst_u,
                            int* __restrict__ bh_i, int* __restrict__ bh_u) {
  __shared__ int h[256];
  int b = blockIdx.x;
  const int* dst;
  int shift;
  int* bh;
  int blk;
  if (b < kNBK) { dst = dst_i; shift = 8; bh = bh_i; blk = b; }
  else          { dst = dst_u; shift = 9; bh = bh_u; blk = b - kNBK; }
  int tid = threadIdx.x;
  h[tid] = 0;
  __syncthreads();
  int chunk = (kE + kNBK - 1) / kNBK;
  int beg = blk * chunk;
  int end = min(kE, beg + chunk);
  for (int i = beg + tid; i < end; i += 256) atomicAdd(&h[dst[i] >> shift], 1);
  __syncthreads();
  bh[blk * 256 + tid] = h[tid];
}

__global__ void binB_kernel(const int* __restrict__ bh_i, int* __restrict__ bo_i,
                            int* __restrict__ base_i, const int* __restrict__ bh_u,
                            int* __restrict__ bo_u, int* __restrict__ base_u) {
  __shared__ int s[256];
  const int* bh;
  int* bo;
  int* base;
  if (blockIdx.x == 0) { bh = bh_i; bo = bo_i; base = base_i; }
  else                 { bh = bh_u; bo = bo_u; base = base_u; }
  int t = threadIdx.x;
  int run = 0;
  for (int b = 0; b < kNBK; ++b) {
    int v = bh[b * 256 + t];
    bo[b * 256 + t] = run;
    run += v;
  }
  s[t] = run;
  __syncthreads();
  for (int m = 1; m < 256; m <<= 1) {
    int tv = 0;
    if (t >= m) tv = s[t - m];
    __syncthreads();
    s[t] += tv;
    __syncthreads();
  }
  base[t] = s[t] - run;
  if (t == 255) base[256] = s[255];
}

__global__ void binC_kernel(const int* __restrict__ src_i, const int* __restrict__ dst_i,
                            const int* __restrict__ bo_i, const int* __restrict__ base_i,
                            unsigned* __restrict__ packed_i, const int* __restrict__ src_u,
                            const int* __restrict__ dst_u, const int* __restrict__ bo_u,
                            const int* __restrict__ base_u, unsigned* __restrict__ packed_u) {
  __shared__ int cur[256];
  int b = blockIdx.x;
  const int *src, *dst, *bo, *base;
  unsigned* packed;
  int shift, blk;
  if (b < kNBK) { src = src_i; dst = dst_i; bo = bo_i; base = base_i; packed = packed_i; shift = 8; blk = b; }
  else          { src = src_u; dst = dst_u; bo = bo_u; base = base_u; packed = packed_u; shift = 9; blk = b - kNBK; }
  int tid = threadIdx.x;
  cur[tid] = base[tid] + bo[blk * 256 + tid];
  __syncthreads();
  int chunk = (kE + kNBK - 1) / kNBK;
  int beg = blk * chunk;
  int end = min(kE, beg + chunk);
  int mask = (1 << shift) - 1;
  for (int i = beg + tid; i < end; i += 256) {
    int d = dst[i];
    int p = atomicAdd(&cur[d >> shift], 1);
    packed[p] = (unsigned)src[i] | ((unsigned)(d & mask) << 17);
  }
}

__launch_bounds__(256)
__global__ void binD_kernel(const unsigned* __restrict__ packed_i, const int* __restrict__ base_i,
                            int* __restrict__ col_i, int* __restrict__ rowptr_i,
                            const unsigned* __restrict__ packed_u, const int* __restrict__ base_u,
                            int* __restrict__ col_u, int* __restrict__ rowptr_u) {
  __shared__ unsigned ent[kCap];
  __shared__ int srt[kCap];
  __shared__ int hist[512];
  __shared__ int cur[512];
  int b = blockIdx.x;
  const unsigned* packed;
  const int* base;
  int* col;
  int* rowptr;
  int bsize, Nd, bb;
  if (b < 196) { packed = packed_i; base = base_i; col = col_i; rowptr = rowptr_i; bsize = 256; Nd = kNI; bb = b; }
  else         { packed = packed_u; base = base_u; col = col_u; rowptr = rowptr_u; bsize = 512; Nd = kNU; bb = b - 196; }
  int tid = threadIdx.x;
  int seg_beg = base[bb], seg_end = base[bb + 1];
  int cnt = seg_end - seg_beg;
  if (cnt > kCap) cnt = kCap;
  hist[tid] = 0;
  hist[tid + 256] = 0;
  __syncthreads();
  for (int i = tid; i < cnt; i += 256) {
    unsigned e = packed[seg_beg + i];
    ent[i] = e;
    atomicAdd(&hist[e >> 17], 1);
  }
  __syncthreads();
  for (int d = 1; d < 512; d <<= 1) {
    int idx = (tid + 1) * 2 * d - 1;
    if (idx < 512) hist[idx] += hist[idx - d];
    __syncthreads();
  }
  if (tid == 0) hist[511] = 0;
  __syncthreads();
  for (int d = 256; d >= 1; d >>= 1) {
    int idx = (tid + 1) * 2 * d - 1;
    if (idx < 512) {
      int tmp = hist[idx - d];
      hist[idx - d] = hist[idx];
      hist[idx] += tmp;
    }
    __syncthreads();
  }
  for (int j = tid; j < bsize; j += 256) {
    int n = bb * bsize + j;
    if (n < Nd) rowptr[n] = seg_beg + hist[j];
  }
  if (bb == 195 && tid == 0) rowptr[Nd] = seg_end;
  cur[tid] = hist[tid];
  cur[tid + 256] = hist[tid + 256];
  __syncthreads();
  for (int i = tid; i < cnt; i += 256) {
    unsigned e = ent[i];
    int p = atomicAdd(&cur[e >> 17], 1);
    srt[p] = (int)(e & 0x1FFFFu);
  }
  __syncthreads();
  for (int i = tid; i < cnt; i += 256) col[seg_beg + i] = srt[i];
}

// ---- pull aggregation v3: quarter-wave per row, 16B/lane gathers, index prefetch ----
__global__ void pull3_kernel(const int* __restrict__ rp_i, const int* __restrict__ col_i,
                             const unsigned short* __restrict__ ft_i, unsigned short* __restrict__ ag_i,
                             const int* __restrict__ rp_u, const int* __restrict__ col_u,
                             const unsigned short* __restrict__ ft_u, unsigned short* __restrict__ ag_u,
                             int nbi) {
  int b = blockIdx.x;
  const int *rowptr, *col;
  const unsigned short* feat;
  unsigned short* agg;
  int Nd, rbase;
  if (b < nbi) { rowptr = rp_i; col = col_i; feat = ft_i; agg = ag_i; Nd = kNI; rbase = b * 16; }
  else         { rowptr = rp_u; col = col_u; feat = ft_u; agg = ag_u; Nd = kNU; rbase = (b - nbi) * 16; }
  int tid = threadIdx.x;
  int wv = tid >> 6;
  int lane = tid & 63;
  int qrow = lane >> 4;
  int qoff = lane & 15;
  int r = rbase + wv * 4 + qrow;
  int beg = 0, end = 0;
  if (r < Nd) {
    beg = rowptr[r];
    end = rowptr[r + 1];
  }
  float acc[8];
#pragma unroll
  for (int c = 0; c < 8; ++c) acc[c] = 0.f;

  int i0 = 0, i1 = 0, i2 = 0, i3 = 0;
  if (beg < end) {  // col padded with 4 zero ints past kE -> over-reads safe
    i0 = col[beg];
    i1 = col[beg + 1];
    i2 = col[beg + 2];
    i3 = col[beg + 3];
  }
  int choff = qoff * 8;
  for (int j = beg; j < end; j += 4) {
    int rem = end - j;
    int n0 = i0, n1 = i1, n2 = i2, n3 = i3;
    if (j + 4 < end) {
      n0 = col[j + 4];
      n1 = col[j + 5];
      n2 = col[j + 6];
      n3 = col[j + 7];
    }
    uint4 g0 = *(const uint4*)(feat + (size_t)i0 * kC + choff);
    uint4 g1 = *(const uint4*)(feat + (size_t)i1 * kC + choff);
    uint4 g2 = *(const uint4*)(feat + (size_t)i2 * kC + choff);
    uint4 g3 = *(const uint4*)(feat + (size_t)i3 * kC + choff);
    if (rem < 2) { g1.x = 0; g1.y = 0; g1.z = 0; g1.w = 0; }
    if (rem < 3) { g2.x = 0; g2.y = 0; g2.z = 0; g2.w = 0; }
    if (rem < 4) { g3.x = 0; g3.y = 0; g3.z = 0; g3.w = 0; }
#define ACC8(g)                                          \
    acc[0] += __uint_as_float((g).x << 16);              \
    acc[1] += __uint_as_float((g).x & 0xffff0000u);      \
    acc[2] += __uint_as_float((g).y << 16);              \
    acc[3] += __uint_as_float((g).y & 0xffff0000u);      \
    acc[4] += __uint_as_float((g).z << 16);              \
    acc[5] += __uint_as_float((g).z & 0xffff0000u);      \
    acc[6] += __uint_as_float((g).w << 16);              \
    acc[7] += __uint_as_float((g).w & 0xffff0000u);
    ACC8(g0)
    ACC8(g1)
    ACC8(g2)
    ACC8(g3)
#undef ACC8
    i0 = n0; i1 = n1; i2 = n2; i3 = n3;
  }
  if (r < Nd) {
    uint4 o;
    o.x = (unsigned)f2bf(acc[0]) | ((unsigned)f2bf(acc[1]) << 16);
    o.y = (unsigned)f2bf(acc[2]) | ((unsigned)f2bf(acc[3]) << 16);
    o.z = (unsigned)f2bf(acc[4]) | ((unsigned)f2bf(acc[5]) << 16);
    o.w = (unsigned)f2bf(acc[6]) | ((unsigned)f2bf(acc[7]) << 16);
    *(uint4*)(agg + (size_t)r * kC + choff) = o;
  }
}

// ---- MFMA GEMM v6: W in LDS (compiler-proof), barrier-free main loop ----
// Block = 512 threads (8 waves), one 128-row tile. Phase 1: stage W (128n x 256k,
// stride 264) into LDS, one barrier. Phase 2: each wave independently computes a
// 16-row x 128-col strip: 8 global A-frag loads + 64 MFMAs (B via ds_read_b128)
// + fully intra-wave LayerNorm (all 128 cols of a row live in this wave).
// Latency hidden by TLP: launch_bounds(512,4) -> VGPR<=128 -> 2 blocks/CU.
__launch_bounds__(512, 4)
__global__ void gemm6_kernel(int nbi,
                             const unsigned short* __restrict__ ag_i, const unsigned short* __restrict__ ft_i,
                             const unsigned short* __restrict__ wc_i, const float* __restrict__ bs_i,
                             const float* __restrict__ gm_i, const float* __restrict__ bt_i,
                             unsigned short* __restrict__ out_i,
                             const unsigned short* __restrict__ ag_u, const unsigned short* __restrict__ ft_u,
                             const unsigned short* __restrict__ wc_u, const float* __restrict__ bs_u,
                             const float* __restrict__ gm_u, const float* __restrict__ bt_u,
                             unsigned short* __restrict__ out_u) {
  __shared__ unsigned short Ws[128 * kWS];  // 67.6 KB
  int b = blockIdx.x;
  const unsigned short *agg, *feat, *wcat;
  const float *bias, *gamma, *beta;
  unsigned short* out;
  int N, row0;
  if (b < nbi) {
    agg = ag_i; feat = ft_i; wcat = wc_i; bias = bs_i; gamma = gm_i; beta = bt_i; out = out_i;
    N = kNI; row0 = b * 128;
  } else {
    agg = ag_u; feat = ft_u; wcat = wc_u; bias = bs_u; gamma = gm_u; beta = bt_u; out = out_u;
    N = kNU; row0 = (b - nbi) * 128;
  }
  int tid = threadIdx.x;
  int lane = tid & 63;
  int wv = tid >> 6;
  int q = lane >> 4;
  int c0 = lane & 15;

  // Phase 1: W -> LDS. 512 threads x 64 shorts: thread t = (n, quarter kp)
  {
    int n = tid >> 2;
    int kp = (tid & 3) * 64;
#pragma unroll
    for (int j = 0; j < 8; ++j) {
      int4 v = *(const int4*)(wcat + n * 256 + kp + j * 8);
      *(int4*)&Ws[n * kWS + kp + j * 8] = v;
    }
  }
  float bcol[8], gcol[8], ecol[8];
#pragma unroll
  for (int nt = 0; nt < 8; ++nt) {
    bcol[nt] = bias[nt * 16 + c0];
    gcol[nt] = gamma[nt * 16 + c0];
    ecol[nt] = beta[nt * 16 + c0];
  }
  __syncthreads();

  // Phase 2: wave-private strip (rows row0+wv*16 .. +16)
  int rs = row0 + wv * 16;
  size_t abase = (size_t)(rs + c0) * kC;  // A-frag m = c0; over-N rows read ws garbage, masked at store
  bf16x8 a[8];
#pragma unroll
  for (int ks = 0; ks < 8; ++ks) {
    const unsigned short* s = (ks < 4) ? agg : feat;
    a[ks] = *(const bf16x8*)(s + abase + (ks & 3) * 32 + q * 8);
  }
  f32x4 acc[8];
#pragma unroll
  for (int nt = 0; nt < 8; ++nt) acc[nt] = (f32x4){0.f, 0.f, 0.f, 0.f};
#pragma unroll
  for (int ks = 0; ks < 8; ++ks) {
#pragma unroll
    for (int nt = 0; nt < 8; ++nt) {
      bf16x8 bfr = *(const bf16x8*)&Ws[(nt * 16 + c0) * kWS + ks * 32 + q * 8];
      acc[nt] = __builtin_amdgcn_mfma_f32_16x16x32_bf16(a[ks], bfr, acc[nt], 0, 0, 0);
    }
  }

  // intra-wave LN epilogue (C/D: col=c0, row=q*4+reg)
#pragma unroll
  for (int reg = 0; reg < 4; ++reg) {
    int row = rs + q * 4 + reg;
    float v[8];
    float s1 = 0.f, s2 = 0.f;
#pragma unroll
    for (int nt = 0; nt < 8; ++nt) {
      float t = acc[nt][reg] + bcol[nt];
      v[nt] = t;
      s1 += t;
      s2 += t * t;
    }
#pragma unroll
    for (int m = 1; m < 16; m <<= 1) {
      s1 += __shfl_xor(s1, m, 64);
      s2 += __shfl_xor(s2, m, 64);
    }
    float mu = s1 * (1.f / 128.f);
    float var = s2 * (1.f / 128.f) - mu * mu;
    float rsq = rsqrtf(var + 1e-5f);
    if (row < N) {
#pragma unroll
      for (int nt = 0; nt < 8; ++nt) {
        float o = fmaxf((v[nt] - mu) * rsq * gcol[nt] + ecol[nt], 0.f);
        unsigned short h = f2bf(o);
        unsigned up = __shfl_xor((unsigned)h, 1, 64);
        if ((lane & 1) == 0) {
          *(unsigned*)(out + (size_t)row * kC + nt * 16 + c0) = (unsigned)h | (up << 16);
        }
      }
    }
  }
}

// ---- final head: out[r] = feat_u[r,:] . lin_w + lin_b ----
__global__ void head_kernel(const unsigned short* __restrict__ fu, const float* __restrict__ lw,
                            const float* __restrict__ lb, float* __restrict__ out) {
  int w = (blockIdx.x * blockDim.x + threadIdx.x) >> 6;
  int lane = threadIdx.x & 63;
  if (w >= kB) return;
  unsigned v = *(const unsigned*)(fu + w * kC + lane * 2);
  float2 ww = *(const float2*)(lw + lane * 2);
  float p = __uint_as_float(v << 16) * ww.x + __uint_as_float(v & 0xffff0000u) * ww.y;
#pragma unroll
  for (int m = 1; m < 64; m <<= 1) p += __shfl_xor(p, m, 64);
  if (lane == 0) out[w] = p + lb[0];
}

extern "C" void kernel_launch(void* const* d_in, const int* in_sizes, int n_in,
                              void* d_out, int out_size, void* d_ws, size_t ws_size,
                              hipStream_t stream) {
  const float* x_user = (const float*)d_in[0];
  const float* x_item = (const float*)d_in[1];
  const int* e_ui_src = (const int*)d_in[2];
  const int* e_ui_dst = (const int*)d_in[3];
  const int* e_iu_src = (const int*)d_in[4];
  const int* e_iu_dst = (const int*)d_in[5];
  const float* w_rel  = (const float*)d_in[6];
  const float* w_root = (const float*)d_in[7];
  const float* bvec   = (const float*)d_in[8];
  const float* ln_g   = (const float*)d_in[9];
  const float* ln_b   = (const float*)d_in[10];
  const float* lin_w  = (const float*)d_in[11];
  const float* lin_b  = (const float*)d_in[12];

  char* p = (char*)d_ws;
  auto carve = [&](size_t bytes) -> char* {
    char* r = p;
    p += (bytes + 255) & ~size_t(255);
    return r;
  };
  unsigned short* fu[2] = {(unsigned short*)carve((size_t)kNU * kC * 2),
                           (unsigned short*)carve((size_t)kNU * kC * 2)};
  unsigned short* fi[2] = {(unsigned short*)carve((size_t)kNI * kC * 2),
                           (unsigned short*)carve((size_t)kNI * kC * 2)};
  unsigned short* agg_i = (unsigned short*)carve((size_t)kNI * kC * 2);
  unsigned short* agg_u = (unsigned short*)carve((size_t)kNU * kC * 2);
  unsigned short* wcat  = (unsigned short*)carve((size_t)4 * 128 * 256 * 2);
  int* bh_i   = (int*)carve((size_t)kNBK * 256 * 4);
  int* bo_i   = (int*)carve((size_t)kNBK * 256 * 4);
  int* bh_u   = (int*)carve((size_t)kNBK * 256 * 4);
  int* bo_u   = (int*)carve((size_t)kNBK * 256 * 4);
  int* base_i = (int*)carve(257 * 4);
  int* base_u = (int*)carve(257 * 4);
  unsigned* packed_i = (unsigned*)carve((size_t)kE * 4);
  unsigned* packed_u = (unsigned*)carve((size_t)kE * 4);
  int* col_i    = (int*)carve((size_t)(kE + 4) * 4);
  int* col_u    = (int*)carve((size_t)(kE + 4) * 4);
  int* rowptr_i = (int*)carve((size_t)(kNI + 1) * 4);
  int* rowptr_u = (int*)carve((size_t)(kNU + 1) * 4);

  int cvtN = (kNU * kC + kNI * kC) / 4;
  cvt_kernel<<<(cvtN + 255) / 256, 256, 0, stream>>>(x_user, x_item, fu[0], fi[0]);
  prep_w_kernel<<<512, 256, 0, stream>>>(w_rel, w_root, wcat);

  binA_kernel<<<2 * kNBK, 256, 0, stream>>>(e_ui_dst, e_iu_dst, bh_i, bh_u);
  binB_kernel<<<2, 256, 0, stream>>>(bh_i, bo_i, base_i, bh_u, bo_u, base_u);
  binC_kernel<<<2 * kNBK, 256, 0, stream>>>(e_ui_src, e_ui_dst, bo_i, base_i, packed_i,
                                            e_iu_src, e_iu_dst, bo_u, base_u, packed_u);
  binD_kernel<<<392, 256, 0, stream>>>(packed_i, base_i, col_i, rowptr_i,
                                       packed_u, base_u, col_u, rowptr_u);
  hipMemsetAsync(col_i + kE, 0, 16, stream);
  hipMemsetAsync(col_u + kE, 0, 16, stream);

  int nbi_p = (kNI + 15) / 16;   // 3125
  int nbu_p = (kNU + 15) / 16;   // 6250
  int nbi_g = (kNI + 127) / 128; // 391
  int nbu_g = (kNU + 127) / 128; // 782

  int cur = 0;
  for (int l = 0; l < 2; ++l) {
    pull3_kernel<<<nbi_p + nbu_p, 256, 0, stream>>>(rowptr_i, col_i, fu[cur], agg_i,
                                                    rowptr_u, col_u, fi[cur], agg_u, nbi_p);
    gemm6_kernel<<<nbi_g + nbu_g, 512, 0, stream>>>(
        nbi_g,
        agg_i, fi[cur], wcat + (size_t)(l * 2 + 0) * 128 * 256,
        bvec + (size_t)(l * 2 + 0) * kC, ln_g + (size_t)(l * 2 + 1) * kC,
        ln_b + (size_t)(l * 2 + 1) * kC, fi[1 - cur],
        agg_u, fu[cur], wcat + (size_t)(l * 2 + 1) * 128 * 256,
        bvec + (size_t)(l * 2 + 1) * kC, ln_g + (size_t)(l * 2 + 0) * kC,
        ln_b + (size_t)(l * 2 + 0) * kC, fu[1 - cur]);
    cur ^= 1;
  }

  head_kernel<<<(kB + 3) / 4, 256, 0, stream>>>(fu[cur], lin_w, lin_b, (float*)d_out);
}

// Round 10
// 318.200 us; speedup vs baseline: 1.3543x; 1.0057x over previous
//
#include <hip/hip_runtime.h>
#include <stdint.h>

static constexpr int kNU = 100000;
static constexpr int kNI = 50000;
static constexpr int kE  = 500000;
static constexpr int kC  = 128;
static constexpr int kB  = 1024;
static constexpr int kNBK = 256;  // binning blocks per direction
static constexpr int kCap = 4096; // max edges per coarse bucket (mean 2560)

typedef __attribute__((ext_vector_type(8))) short bf16x8;
typedef __attribute__((ext_vector_type(4))) float f32x4;

__device__ __forceinline__ unsigned short f2bf(float f) {
  unsigned u = __float_as_uint(f);
  unsigned r = (u + 0x7fffu + ((u >> 16) & 1u)) >> 16;
  return (unsigned short)r;
}

// ---- fp32 -> bf16 feature conversion (both tables in one launch) ----
__global__ void cvt_kernel(const float* __restrict__ xu, const float* __restrict__ xi,
                           unsigned short* __restrict__ fu, unsigned short* __restrict__ fi) {
  int i = blockIdx.x * blockDim.x + threadIdx.x;  // float4 index
  const int nu4 = kNU * kC / 4;
  const int ni4 = kNI * kC / 4;
  if (i < nu4) {
    float4 v = ((const float4*)xu)[i];
    ushort4 o; o.x = f2bf(v.x); o.y = f2bf(v.y); o.z = f2bf(v.z); o.w = f2bf(v.w);
    ((ushort4*)fu)[i] = o;
  } else if (i < nu4 + ni4) {
    int j = i - nu4;
    float4 v = ((const float4*)xi)[j];
    ushort4 o; o.x = f2bf(v.x); o.y = f2bf(v.y); o.z = f2bf(v.z); o.w = f2bf(v.w);
    ((ushort4*)fi)[j] = o;
  }
}

// ---- weight prep: wcat[m][n][k] bf16, m = l*2+t; k<128 -> w_rel^T, k>=128 -> w_root^T ----
__global__ void prep_w_kernel(const float* __restrict__ wrel, const float* __restrict__ wroot,
                              unsigned short* __restrict__ wcat) {
  int id = blockIdx.x * 256 + threadIdx.x;  // 4*128*256 = 131072
  int m = id >> 15;
  int n = (id >> 8) & 127;
  int k = id & 255;
  float v = (k < 128) ? wrel[(m * 128 + k) * 128 + n] : wroot[(m * 128 + (k - 128)) * 128 + n];
  wcat[id] = f2bf(v);
}

// ================= LDS-binned CSR build (no global atomics), both dirs =================
__global__ void binA_kernel(const int* __restrict__ dst_i, const int* __restrict__ dst_u,
                            int* __restrict__ bh_i, int* __restrict__ bh_u) {
  __shared__ int h[256];
  int b = blockIdx.x;
  const int* dst;
  int shift;
  int* bh;
  int blk;
  if (b < kNBK) { dst = dst_i; shift = 8; bh = bh_i; blk = b; }
  else          { dst = dst_u; shift = 9; bh = bh_u; blk = b - kNBK; }
  int tid = threadIdx.x;
  h[tid] = 0;
  __syncthreads();
  int chunk = (kE + kNBK - 1) / kNBK;
  int beg = blk * chunk;
  int end = min(kE, beg + chunk);
  for (int i = beg + tid; i < end; i += 256) atomicAdd(&h[dst[i] >> shift], 1);
  __syncthreads();
  bh[blk * 256 + tid] = h[tid];
}

__global__ void binB_kernel(const int* __restrict__ bh_i, int* __restrict__ bo_i,
                            int* __restrict__ base_i, const int* __restrict__ bh_u,
                            int* __restrict__ bo_u, int* __restrict__ base_u) {
  __shared__ int s[256];
  const int* bh;
  int* bo;
  int* base;
  if (blockIdx.x == 0) { bh = bh_i; bo = bo_i; base = base_i; }
  else                 { bh = bh_u; bo = bo_u; base = base_u; }
  int t = threadIdx.x;
  int run = 0;
  for (int b = 0; b < kNBK; ++b) {
    int v = bh[b * 256 + t];
    bo[b * 256 + t] = run;
    run += v;
  }
  s[t] = run;
  __syncthreads();
  for (int m = 1; m < 256; m <<= 1) {
    int tv = 0;
    if (t >= m) tv = s[t - m];
    __syncthreads();
    s[t] += tv;
    __syncthreads();
  }
  base[t] = s[t] - run;
  if (t == 255) base[256] = s[255];
}

__global__ void binC_kernel(const int* __restrict__ src_i, const int* __restrict__ dst_i,
                            const int* __restrict__ bo_i, const int* __restrict__ base_i,
                            unsigned* __restrict__ packed_i, const int* __restrict__ src_u,
                            const int* __restrict__ dst_u, const int* __restrict__ bo_u,
                            const int* __restrict__ base_u, unsigned* __restrict__ packed_u) {
  __shared__ int cur[256];
  int b = blockIdx.x;
  const int *src, *dst, *bo, *base;
  unsigned* packed;
  int shift, blk;
  if (b < kNBK) { src = src_i; dst = dst_i; bo = bo_i; base = base_i; packed = packed_i; shift = 8; blk = b; }
  else          { src = src_u; dst = dst_u; bo = bo_u; base = base_u; packed = packed_u; shift = 9; blk = b - kNBK; }
  int tid = threadIdx.x;
  cur[tid] = base[tid] + bo[blk * 256 + tid];
  __syncthreads();
  int chunk = (kE + kNBK - 1) / kNBK;
  int beg = blk * chunk;
  int end = min(kE, beg + chunk);
  int mask = (1 << shift) - 1;
  for (int i = beg + tid; i < end; i += 256) {
    int d = dst[i];
    int p = atomicAdd(&cur[d >> shift], 1);
    packed[p] = (unsigned)src[i] | ((unsigned)(d & mask) << 17);
  }
}

__launch_bounds__(256)
__global__ void binD_kernel(const unsigned* __restrict__ packed_i, const int* __restrict__ base_i,
                            int* __restrict__ col_i, int* __restrict__ rowptr_i,
                            const unsigned* __restrict__ packed_u, const int* __restrict__ base_u,
                            int* __restrict__ col_u, int* __restrict__ rowptr_u) {
  __shared__ unsigned ent[kCap];
  __shared__ int srt[kCap];
  __shared__ int hist[512];
  __shared__ int cur[512];
  int b = blockIdx.x;
  const unsigned* packed;
  const int* base;
  int* col;
  int* rowptr;
  int bsize, Nd, bb;
  if (b < 196) { packed = packed_i; base = base_i; col = col_i; rowptr = rowptr_i; bsize = 256; Nd = kNI; bb = b; }
  else         { packed = packed_u; base = base_u; col = col_u; rowptr = rowptr_u; bsize = 512; Nd = kNU; bb = b - 196; }
  int tid = threadIdx.x;
  int seg_beg = base[bb], seg_end = base[bb + 1];
  int cnt = seg_end - seg_beg;
  if (cnt > kCap) cnt = kCap;
  hist[tid] = 0;
  hist[tid + 256] = 0;
  __syncthreads();
  for (int i = tid; i < cnt; i += 256) {
    unsigned e = packed[seg_beg + i];
    ent[i] = e;
    atomicAdd(&hist[e >> 17], 1);
  }
  __syncthreads();
  for (int d = 1; d < 512; d <<= 1) {
    int idx = (tid + 1) * 2 * d - 1;
    if (idx < 512) hist[idx] += hist[idx - d];
    __syncthreads();
  }
  if (tid == 0) hist[511] = 0;
  __syncthreads();
  for (int d = 256; d >= 1; d >>= 1) {
    int idx = (tid + 1) * 2 * d - 1;
    if (idx < 512) {
      int tmp = hist[idx - d];
      hist[idx - d] = hist[idx];
      hist[idx] += tmp;
    }
    __syncthreads();
  }
  for (int j = tid; j < bsize; j += 256) {
    int n = bb * bsize + j;
    if (n < Nd) rowptr[n] = seg_beg + hist[j];
  }
  if (bb == 195 && tid == 0) rowptr[Nd] = seg_end;
  cur[tid] = hist[tid];
  cur[tid + 256] = hist[tid + 256];
  __syncthreads();
  for (int i = tid; i < cnt; i += 256) {
    unsigned e = ent[i];
    int p = atomicAdd(&cur[e >> 17], 1);
    srt[p] = (int)(e & 0x1FFFFu);
  }
  __syncthreads();
  for (int i = tid; i < cnt; i += 256) col[seg_beg + i] = srt[i];
}

// ---- pull aggregation v3: quarter-wave per row, 16B/lane gathers, index prefetch ----
__global__ void pull3_kernel(const int* __restrict__ rp_i, const int* __restrict__ col_i,
                             const unsigned short* __restrict__ ft_i, unsigned short* __restrict__ ag_i,
                             const int* __restrict__ rp_u, const int* __restrict__ col_u,
                             const unsigned short* __restrict__ ft_u, unsigned short* __restrict__ ag_u,
                             int nbi) {
  int b = blockIdx.x;
  const int *rowptr, *col;
  const unsigned short* feat;
  unsigned short* agg;
  int Nd, rbase;
  if (b < nbi) { rowptr = rp_i; col = col_i; feat = ft_i; agg = ag_i; Nd = kNI; rbase = b * 16; }
  else         { rowptr = rp_u; col = col_u; feat = ft_u; agg = ag_u; Nd = kNU; rbase = (b - nbi) * 16; }
  int tid = threadIdx.x;
  int wv = tid >> 6;
  int lane = tid & 63;
  int qrow = lane >> 4;
  int qoff = lane & 15;
  int r = rbase + wv * 4 + qrow;
  int beg = 0, end = 0;
  if (r < Nd) {
    beg = rowptr[r];
    end = rowptr[r + 1];
  }
  float acc[8];
#pragma unroll
  for (int c = 0; c < 8; ++c) acc[c] = 0.f;

  int i0 = 0, i1 = 0, i2 = 0, i3 = 0;
  if (beg < end) {  // col padded with 4 zero ints past kE -> over-reads safe
    i0 = col[beg];
    i1 = col[beg + 1];
    i2 = col[beg + 2];
    i3 = col[beg + 3];
  }
  int choff = qoff * 8;
  for (int j = beg; j < end; j += 4) {
    int rem = end - j;
    int n0 = i0, n1 = i1, n2 = i2, n3 = i3;
    if (j + 4 < end) {
      n0 = col[j + 4];
      n1 = col[j + 5];
      n2 = col[j + 6];
      n3 = col[j + 7];
    }
    uint4 g0 = *(const uint4*)(feat + (size_t)i0 * kC + choff);
    uint4 g1 = *(const uint4*)(feat + (size_t)i1 * kC + choff);
    uint4 g2 = *(const uint4*)(feat + (size_t)i2 * kC + choff);
    uint4 g3 = *(const uint4*)(feat + (size_t)i3 * kC + choff);
    if (rem < 2) { g1.x = 0; g1.y = 0; g1.z = 0; g1.w = 0; }
    if (rem < 3) { g2.x = 0; g2.y = 0; g2.z = 0; g2.w = 0; }
    if (rem < 4) { g3.x = 0; g3.y = 0; g3.z = 0; g3.w = 0; }
#define ACC8(g)                                          \
    acc[0] += __uint_as_float((g).x << 16);              \
    acc[1] += __uint_as_float((g).x & 0xffff0000u);      \
    acc[2] += __uint_as_float((g).y << 16);              \
    acc[3] += __uint_as_float((g).y & 0xffff0000u);      \
    acc[4] += __uint_as_float((g).z << 16);              \
    acc[5] += __uint_as_float((g).z & 0xffff0000u);      \
    acc[6] += __uint_as_float((g).w << 16);              \
    acc[7] += __uint_as_float((g).w & 0xffff0000u);
    ACC8(g0)
    ACC8(g1)
    ACC8(g2)
    ACC8(g3)
#undef ACC8
    i0 = n0; i1 = n1; i2 = n2; i3 = n3;
  }
  if (r < Nd) {
    uint4 o;
    o.x = (unsigned)f2bf(acc[0]) | ((unsigned)f2bf(acc[1]) << 16);
    o.y = (unsigned)f2bf(acc[2]) | ((unsigned)f2bf(acc[3]) << 16);
    o.z = (unsigned)f2bf(acc[4]) | ((unsigned)f2bf(acc[5]) << 16);
    o.w = (unsigned)f2bf(acc[6]) | ((unsigned)f2bf(acc[7]) << 16);
    *(uint4*)(agg + (size_t)r * kC + choff) = o;
  }
}

// ---- MFMA GEMM v7: gemm6 + XOR-swizzled W LDS layout (bank-conflict-free) ----
// Row n's 16B chunk j stored at physical chunk j^(n&7); row stride 256 shorts
// (base ≡ 0 mod 32 banks, all spreading via swizzle). Read: lane (q,c0) fetches
// chunk (ks*4+q)^(c0&7) -> exactly 8 lanes per bank-quad = b128 structural floor.
__launch_bounds__(512, 4)
__global__ void gemm7_kernel(int nbi,
                             const unsigned short* __restrict__ ag_i, const unsigned short* __restrict__ ft_i,
                             const unsigned short* __restrict__ wc_i, const float* __restrict__ bs_i,
                             const float* __restrict__ gm_i, const float* __restrict__ bt_i,
                             unsigned short* __restrict__ out_i,
                             const unsigned short* __restrict__ ag_u, const unsigned short* __restrict__ ft_u,
                             const unsigned short* __restrict__ wc_u, const float* __restrict__ bs_u,
                             const float* __restrict__ gm_u, const float* __restrict__ bt_u,
                             unsigned short* __restrict__ out_u) {
  __shared__ unsigned short Ws[128 * 256];  // 64 KB, swizzled
  int b = blockIdx.x;
  const unsigned short *agg, *feat, *wcat;
  const float *bias, *gamma, *beta;
  unsigned short* out;
  int N, row0;
  if (b < nbi) {
    agg = ag_i; feat = ft_i; wcat = wc_i; bias = bs_i; gamma = gm_i; beta = bt_i; out = out_i;
    N = kNI; row0 = b * 128;
  } else {
    agg = ag_u; feat = ft_u; wcat = wc_u; bias = bs_u; gamma = gm_u; beta = bt_u; out = out_u;
    N = kNU; row0 = (b - nbi) * 128;
  }
  int tid = threadIdx.x;
  int lane = tid & 63;
  int wv = tid >> 6;
  int q = lane >> 4;
  int c0 = lane & 15;

  // Phase 1: W -> LDS with XOR swizzle. thread t: row n=t>>2, chunks (t&3)*8 ..+8
  {
    int n = tid >> 2;
    int cbase = (tid & 3) * 8;
    int sw = n & 7;
#pragma unroll
    for (int j = 0; j < 8; ++j) {
      int ch = cbase + j;
      int4 v = *(const int4*)(wcat + n * 256 + ch * 8);
      *(int4*)&Ws[n * 256 + (ch ^ sw) * 8] = v;
    }
  }
  float bcol[8], gcol[8], ecol[8];
#pragma unroll
  for (int nt = 0; nt < 8; ++nt) {
    bcol[nt] = bias[nt * 16 + c0];
    gcol[nt] = gamma[nt * 16 + c0];
    ecol[nt] = beta[nt * 16 + c0];
  }
  __syncthreads();

  // Phase 2: wave-private strip (rows row0+wv*16 .. +16)
  int rs = row0 + wv * 16;
  size_t abase = (size_t)(rs + c0) * kC;  // A-frag m = c0; over-N rows read ws garbage, masked at store
  bf16x8 a[8];
#pragma unroll
  for (int ks = 0; ks < 8; ++ks) {
    const unsigned short* s = (ks < 4) ? agg : feat;
    a[ks] = *(const bf16x8*)(s + abase + (ks & 3) * 32 + q * 8);
  }
  f32x4 acc[8];
#pragma unroll
  for (int nt = 0; nt < 8; ++nt) acc[nt] = (f32x4){0.f, 0.f, 0.f, 0.f};
  int rsw = c0 & 7;
#pragma unroll
  for (int ks = 0; ks < 8; ++ks) {
    int chp = ((ks * 4 + q) ^ rsw) * 8;
#pragma unroll
    for (int nt = 0; nt < 8; ++nt) {
      bf16x8 bfr = *(const bf16x8*)&Ws[(nt * 16 + c0) * 256 + chp];
      acc[nt] = __builtin_amdgcn_mfma_f32_16x16x32_bf16(a[ks], bfr, acc[nt], 0, 0, 0);
    }
  }

  // intra-wave LN epilogue (C/D: col=c0, row=q*4+reg)
#pragma unroll
  for (int reg = 0; reg < 4; ++reg) {
    int row = rs + q * 4 + reg;
    float v[8];
    float s1 = 0.f, s2 = 0.f;
#pragma unroll
    for (int nt = 0; nt < 8; ++nt) {
      float t = acc[nt][reg] + bcol[nt];
      v[nt] = t;
      s1 += t;
      s2 += t * t;
    }
#pragma unroll
    for (int m = 1; m < 16; m <<= 1) {
      s1 += __shfl_xor(s1, m, 64);
      s2 += __shfl_xor(s2, m, 64);
    }
    float mu = s1 * (1.f / 128.f);
    float var = s2 * (1.f / 128.f) - mu * mu;
    float rsq = rsqrtf(var + 1e-5f);
    if (row < N) {
#pragma unroll
      for (int nt = 0; nt < 8; ++nt) {
        float o = fmaxf((v[nt] - mu) * rsq * gcol[nt] + ecol[nt], 0.f);
        unsigned short h = f2bf(o);
        unsigned up = __shfl_xor((unsigned)h, 1, 64);
        if ((lane & 1) == 0) {
          *(unsigned*)(out + (size_t)row * kC + nt * 16 + c0) = (unsigned)h | (up << 16);
        }
      }
    }
  }
}

// ---- final head: out[r] = feat_u[r,:] . lin_w + lin_b ----
__global__ void head_kernel(const unsigned short* __restrict__ fu, const float* __restrict__ lw,
                            const float* __restrict__ lb, float* __restrict__ out) {
  int w = (blockIdx.x * blockDim.x + threadIdx.x) >> 6;
  int lane = threadIdx.x & 63;
  if (w >= kB) return;
  unsigned v = *(const unsigned*)(fu + w * kC + lane * 2);
  float2 ww = *(const float2*)(lw + lane * 2);
  float p = __uint_as_float(v << 16) * ww.x + __uint_as_float(v & 0xffff0000u) * ww.y;
#pragma unroll
  for (int m = 1; m < 64; m <<= 1) p += __shfl_xor(p, m, 64);
  if (lane == 0) out[w] = p + lb[0];
}

extern "C" void kernel_launch(void* const* d_in, const int* in_sizes, int n_in,
                              void* d_out, int out_size, void* d_ws, size_t ws_size,
                              hipStream_t stream) {
  const float* x_user = (const float*)d_in[0];
  const float* x_item = (const float*)d_in[1];
  const int* e_ui_src = (const int*)d_in[2];
  const int* e_ui_dst = (const int*)d_in[3];
  const int* e_iu_src = (const int*)d_in[4];
  const int* e_iu_dst = (const int*)d_in[5];
  const float* w_rel  = (const float*)d_in[6];
  const float* w_root = (const float*)d_in[7];
  const float* bvec   = (const float*)d_in[8];
  const float* ln_g   = (const float*)d_in[9];
  const float* ln_b   = (const float*)d_in[10];
  const float* lin_w  = (const float*)d_in[11];
  const float* lin_b  = (const float*)d_in[12];

  char* p = (char*)d_ws;
  auto carve = [&](size_t bytes) -> char* {
    char* r = p;
    p += (bytes + 255) & ~size_t(255);
    return r;
  };
  unsigned short* fu[2] = {(unsigned short*)carve((size_t)kNU * kC * 2),
                           (unsigned short*)carve((size_t)kNU * kC * 2)};
  unsigned short* fi[2] = {(unsigned short*)carve((size_t)kNI * kC * 2),
                           (unsigned short*)carve((size_t)kNI * kC * 2)};
  unsigned short* agg_i = (unsigned short*)carve((size_t)kNI * kC * 2);
  unsigned short* agg_u = (unsigned short*)carve((size_t)kNU * kC * 2);
  unsigned short* wcat  = (unsigned short*)carve((size_t)4 * 128 * 256 * 2);
  int* bh_i   = (int*)carve((size_t)kNBK * 256 * 4);
  int* bo_i   = (int*)carve((size_t)kNBK * 256 * 4);
  int* bh_u   = (int*)carve((size_t)kNBK * 256 * 4);
  int* bo_u   = (int*)carve((size_t)kNBK * 256 * 4);
  int* base_i = (int*)carve(257 * 4);
  int* base_u = (int*)carve(257 * 4);
  unsigned* packed_i = (unsigned*)carve((size_t)kE * 4);
  unsigned* packed_u = (unsigned*)carve((size_t)kE * 4);
  int* col_i    = (int*)carve((size_t)(kE + 4) * 4);
  int* col_u    = (int*)carve((size_t)(kE + 4) * 4);
  int* rowptr_i = (int*)carve((size_t)(kNI + 1) * 4);
  int* rowptr_u = (int*)carve((size_t)(kNU + 1) * 4);

  int cvtN = (kNU * kC + kNI * kC) / 4;
  cvt_kernel<<<(cvtN + 255) / 256, 256, 0, stream>>>(x_user, x_item, fu[0], fi[0]);
  prep_w_kernel<<<512, 256, 0, stream>>>(w_rel, w_root, wcat);

  binA_kernel<<<2 * kNBK, 256, 0, stream>>>(e_ui_dst, e_iu_dst, bh_i, bh_u);
  binB_kernel<<<2, 256, 0, stream>>>(bh_i, bo_i, base_i, bh_u, bo_u, base_u);
  binC_kernel<<<2 * kNBK, 256, 0, stream>>>(e_ui_src, e_ui_dst, bo_i, base_i, packed_i,
                                            e_iu_src, e_iu_dst, bo_u, base_u, packed_u);
  binD_kernel<<<392, 256, 0, stream>>>(packed_i, base_i, col_i, rowptr_i,
                                       packed_u, base_u, col_u, rowptr_u);
  hipMemsetAsync(col_i + kE, 0, 16, stream);
  hipMemsetAsync(col_u + kE, 0, 16, stream);

  int nbi_p = (kNI + 15) / 16;   // 3125
  int nbu_p = (kNU + 15) / 16;   // 6250
  int nbi_g = (kNI + 127) / 128; // 391
  int nbu_g = (kNU + 127) / 128; // 782

  int cur = 0;
  for (int l = 0; l < 2; ++l) {
    pull3_kernel<<<nbi_p + nbu_p, 256, 0, stream>>>(rowptr_i, col_i, fu[cur], agg_i,
                                                    rowptr_u, col_u, fi[cur], agg_u, nbi_p);
    gemm7_kernel<<<nbi_g + nbu_g, 512, 0, stream>>>(
        nbi_g,
        agg_i, fi[cur], wcat + (size_t)(l * 2 + 0) * 128 * 256,
        bvec + (size_t)(l * 2 + 0) * kC, ln_g + (size_t)(l * 2 + 1) * kC,
        ln_b + (size_t)(l * 2 + 1) * kC, fi[1 - cur],
        agg_u, fu[cur], wcat + (size_t)(l * 2 + 1) * 128 * 256,
        bvec + (size_t)(l * 2 + 1) * kC, ln_g + (size_t)(l * 2 + 0) * kC,
        ln_b + (size_t)(l * 2 + 0) * kC, fu[1 - cur]);
    cur ^= 1;
  }

  head_kernel<<<(kB + 3) / 4, 256, 0, stream>>>(fu[cur], lin_w, lin_b, (float*)d_out);
}